// Round 25
// baseline (210.090 us; speedup 1.0000x reference)
//
#include <hip/hip_runtime.h>
#include <hip/hip_bf16.h>
#include <stdint.h>

#define B_ 4
#define S_ 2048
#define D_ 1024
#define H_ 16

typedef __attribute__((ext_vector_type(4))) float f32x4;
typedef __attribute__((ext_vector_type(16))) float f32x16;
typedef __attribute__((ext_vector_type(8))) short short8;
typedef __attribute__((ext_vector_type(8))) unsigned short ushort8;
typedef __attribute__((ext_vector_type(4))) unsigned int u32x4;
typedef unsigned short u16;
typedef unsigned int u32;

__device__ __forceinline__ u16 f2bf(float f){
  return __builtin_bit_cast(u16, __hip_bfloat16(f));
}
__device__ __forceinline__ u32 pk2bf(float a, float b){
  return (u32)f2bf(a) | ((u32)f2bf(b) << 16);
}
// raw v_exp_f32: skips the non-fast-math denormal guard sequence
__device__ __forceinline__ float rexp2(float x){
  float r; asm("v_exp_f32 %0, %1" : "=v"(r) : "v"(x)); return r;
}
// HW packed f32->bf16 pair convert: dst.lo=bf16(a), dst.hi=bf16(b)
__device__ __forceinline__ u32 cvtpk(float a, float b){
  u32 r; asm("v_cvt_pk_bf16_f32 %0, %1, %2" : "=v"(r) : "v"(a), "v"(b)); return r;
}
__device__ __forceinline__ f32x4 mfma16(short8 a, short8 b, f32x4 c){
  return __builtin_amdgcn_mfma_f32_16x16x32_bf16(a, b, c, 0, 0, 0);
}
__device__ __forceinline__ f32x16 mfma32(short8 a, short8 b, f32x16 c){
  return __builtin_amdgcn_mfma_f32_32x32x16_bf16(a, b, c, 0, 0, 0);
}
// swap upper half of x with lower half of y (v_permlane32_swap_b32)
__device__ __forceinline__ void plswap(u32 &x, u32 &y){
  asm volatile("v_permlane32_swap_b32 %0, %1" : "+v"(x), "+v"(y));
}
__device__ __forceinline__ void gload16(const u16* g, u16* l){
  __builtin_amdgcn_global_load_lds((const __attribute__((address_space(1))) u32*)g,
                                   (__attribute__((address_space(3))) u32*)l, 16, 0, 0);
}

// ---------------- prep: 4 weight cvt + rope table (x-cvt fused into GEMMs) -
__global__ __launch_bounds__(256) void prep_kernel(const float* __restrict__ w0, const float* __restrict__ w1,
                                                   const float* __restrict__ w2, const float* __restrict__ w3,
                                                   u16* __restrict__ o0, u16* __restrict__ o1,
                                                   u16* __restrict__ o2, u16* __restrict__ o3,
                                                   float2* __restrict__ tab){
  const int gid = blockIdx.x;
  if (gid < 4096){
    const int which = gid >> 10;
    const float* in = (which==0) ? w0 : (which==1) ? w1 : (which==2) ? w2 : w3;
    u16* out = (which==0) ? o0 : (which==1) ? o1 : (which==2) ? o2 : o3;
    const int i = (gid & 1023) * 256 + threadIdx.x;
    float4 v = reinterpret_cast<const float4*>(in)[i];
    uint2 o; o.x = pk2bf(v.x, v.y); o.y = pk2bf(v.z, v.w);
    reinterpret_cast<uint2*>(out)[i] = o;
  } else {
    const int idx = (gid - 4096) * 256 + threadIdx.x;   // 65536
    const int i = idx & 31, s = idx >> 5;
    const float ang = (float)s * __builtin_exp2f((float)i * -0.41524101186092032f);
    float sn, cs;
    __sincosf(ang, &sn, &cs);
    tab[idx] = make_float2(cs, sn);
  }
}

// ---------------- merged Q+K projection GEMM (A read as fp32 directly) -----
// A (=x fp32) staged via regs: load fp32 -> cvt_pk -> ds_write_b128 into the
// write-side-swizzled LDS tile (both-sides XOR, rule-21-safe since we control
// the write address directly). A-loads issued BEFORE the B gload_lds so the
// ds_write's vmcnt wait doesn't drain the B prefetch. Same dbuf+__syncthreads.
// 8-wave 128x128 tile, BK=32 (3-matrix dbuf = 48 KB), 4-row XOR swizzle.
// Epilogue: RoPE for Q (x QS) and K.
__global__ __launch_bounds__(512) void gemm_qk(const float* __restrict__ Ax,
                                               const u16* __restrict__ Wq,
                                               const u16* __restrict__ Wk,
                                               u16* __restrict__ Qh,
                                               u16* __restrict__ Kh,
                                               const float2* __restrict__ tab){
  __shared__ __align__(16) u16 As [2][128*32];   // 16 KB
  __shared__ __align__(16) u16 Bqs[2][128*32];   // 16 KB
  __shared__ __align__(16) u16 Bks[2][128*32];   // 16 KB
  const int K = 1024;
  const int tid = threadIdx.x;
  const int lane = tid & 63, wid = tid >> 6;      // 8 waves
  const int l16 = lane & 15, lq = lane >> 4;
  const int m0 = blockIdx.x * 128, n0 = blockIdx.y * 128;
  const int wr = (wid >> 2) * 64, wc = (wid & 3) * 32;
  // staging: thread t -> row t>>2 (0..127); B source col swizzled (gload),
  // A written directly at swizzled LDS address.
  const int row_s = tid >> 2;
  const int c0 = (tid & 3) * 8;
  const int csw = c0 ^ ((row_s & 3) << 3);
  const float* Ag = Ax + (size_t)(m0 + row_s) * K + c0;        // fp32, no swz
  const u16* Qg = Wq + (size_t)(n0 + row_s) * K + csw;
  const u16* Kg = Wk + (size_t)(n0 + row_s) * K + csw;
  const int awr = row_s*32 + csw;                 // A ds_write addr (u16 idx)
  const int wb = wid * 512;                       // wave staging base (u16)
  const int rsw = (l16 & 3) << 3;                 // read-side swizzle
  // prologue: stage k=0 into buf 0
  {
    float4 a0 = *reinterpret_cast<const float4*>(Ag);
    float4 a1 = *reinterpret_cast<const float4*>(Ag + 4);
    gload16(Qg, &Bqs[0][wb]);
    gload16(Kg, &Bks[0][wb]);
    u32x4 w; w[0]=pk2bf(a0.x,a0.y); w[1]=pk2bf(a0.z,a0.w);
    w[2]=pk2bf(a1.x,a1.y); w[3]=pk2bf(a1.z,a1.w);
    *reinterpret_cast<u32x4*>(&As[0][awr]) = w;
  }
  __syncthreads();
  f32x4 accQ[4][2] = {}, accK[4][2] = {};
  int cur = 0;
  const int NS = 32;   // K/32 steps
#pragma unroll 1
  for (int ks = 0; ks < NS; ++ks){
    float4 a0, a1;
    if (ks + 1 < NS){
      const int kn = (ks + 1) * 32;
      a0 = *reinterpret_cast<const float4*>(Ag + kn);      // issue A first
      a1 = *reinterpret_cast<const float4*>(Ag + kn + 4);
      gload16(Qg + kn, &Bqs[cur^1][wb]);                    // then B prefetch
      gload16(Kg + kn, &Bks[cur^1][wb]);
    }
    const u16* Ac  = &As [cur][0];
    const u16* Bqc = &Bqs[cur][0];
    const u16* Bkc = &Bks[cur][0];
    short8 af[4], bq[2], bk[2];
#pragma unroll
    for (int i=0;i<4;i++)
      af[i] = *reinterpret_cast<const short8*>(Ac + (wr + i*16 + l16)*32 + ((lq*8) ^ rsw));
#pragma unroll
    for (int j=0;j<2;j++){
      bq[j] = *reinterpret_cast<const short8*>(Bqc + (wc + j*16 + l16)*32 + ((lq*8) ^ rsw));
      bk[j] = *reinterpret_cast<const short8*>(Bkc + (wc + j*16 + l16)*32 + ((lq*8) ^ rsw));
    }
    __builtin_amdgcn_s_setprio(1);
#pragma unroll
    for (int i=0;i<4;i++)
#pragma unroll
      for (int j=0;j<2;j++){
        accQ[i][j] = mfma16(af[i], bq[j], accQ[i][j]);
        accK[i][j] = mfma16(af[i], bk[j], accK[i][j]);
      }
    __builtin_amdgcn_s_setprio(0);
    if (ks + 1 < NS){   // write A regs into buf^1 (covered by HBM latency)
      u32x4 w; w[0]=pk2bf(a0.x,a0.y); w[1]=pk2bf(a0.z,a0.w);
      w[2]=pk2bf(a1.x,a1.y); w[3]=pk2bf(a1.z,a1.w);
      *reinterpret_cast<u32x4*>(&As[cur^1][awr]) = w;
    }
    __syncthreads();   // prefetch + A-write landed; all waves done with cur
    cur ^= 1;
  }
  const float QS = 0.18033688011112043f;  // 0.125 * log2(e)
#pragma unroll
  for (int i=0;i<4;i++){
#pragma unroll
    for (int j=0;j<2;j++){
#pragma unroll
      for (int r=0;r<4;r++){
        const int m = m0 + wr + i*16 + lq*4 + r;
        const int n = n0 + wc + j*16 + l16;
        const int b = m >> 11, s = m & 2047;    // S_=2048
        const int h = n >> 6,  hd = n & 63;     // HD=64
        const float2 t = tab[(s << 5) + (hd >> 1)];
        const size_t dst = (((size_t)(b*H_ + h) * S_ + s) << 6) + hd;
        {
          float v = accQ[i][j][r];
          const float partner = __shfl_xor(v, 1, 64);
          const float pm = (hd & 1) ? partner : -partner;
          Qh[dst] = f2bf(fmaf(v, t.x, pm * t.y) * QS);
        }
        {
          float v = accK[i][j][r];
          const float partner = __shfl_xor(v, 1, 64);
          const float pm = (hd & 1) ? partner : -partner;
          Kh[dst] = f2bf(fmaf(v, t.x, pm * t.y));
        }
      }
    }
  }
}

// ---------------- GEMM: C[M,N] = A[M,K] * B[N,K]^T --------------------------
// 8-wave 128x128 tile, BK=64, dbuf via __syncthreads, both-sides XOR swizzle.
// AF32: A read as fp32 directly (reg-staged cvt_pk + ds_write, x-cvt fused).
// MODE 2: f32 [M][N];  MODE 4: bf16 V^T -> [BH][HD=64][S].
template<int MODE, bool AF32>
__global__ __launch_bounds__(512) void gemm_bt(const u16* __restrict__ A,
                                               const float* __restrict__ Af,
                                               const u16* __restrict__ Bw,
                                               void* __restrict__ C,
                                               int M, int N, int K){
  __shared__ __align__(16) u16 As[2][128*64];   // 32 KB
  __shared__ __align__(16) u16 Bs[2][128*64];   // 32 KB
  const int tid = threadIdx.x;
  const int lane = tid & 63, wid = tid >> 6;      // 8 waves
  const int l16 = lane & 15, lq = lane >> 4;
  const int m0 = blockIdx.x * 128, n0 = blockIdx.y * 128;
  const int wr = (wid >> 2) * 64, wc = (wid & 3) * 32;
  const int row_s = tid >> 3;                     // 0..63
  const int c0 = (tid & 7) * 8;
  const int csw = c0 ^ ((row_s & 7) << 3);
  const u16*   Ag0 = A  + (size_t)(m0 + row_s     ) * K + csw;
  const u16*   Ag1 = A  + (size_t)(m0 + 64 + row_s) * K + csw;
  const float* Af0 = Af + (size_t)(m0 + row_s     ) * K + c0;   // fp32, no swz
  const float* Af1 = Af + (size_t)(m0 + 64 + row_s) * K + c0;
  const u16* Bg0 = Bw + (size_t)(n0 + row_s     ) * K + csw;
  const u16* Bg1 = Bw + (size_t)(n0 + 64 + row_s) * K + csw;
  const int awr = row_s*64 + csw;                 // A ds_write addr (u16 idx)
  const int wb = wid * 512;                       // wave staging base (u16)
  const int rsw = (l16 & 7) << 3;                 // read-side swizzle
  // prologue: stage k=0 into buf 0
  if (AF32){
    float4 a0 = *reinterpret_cast<const float4*>(Af0);
    float4 a1 = *reinterpret_cast<const float4*>(Af0 + 4);
    float4 a2 = *reinterpret_cast<const float4*>(Af1);
    float4 a3 = *reinterpret_cast<const float4*>(Af1 + 4);
    gload16(Bg0, &Bs[0][wb]);
    gload16(Bg1, &Bs[0][4096 + wb]);
    u32x4 w0, w1;
    w0[0]=pk2bf(a0.x,a0.y); w0[1]=pk2bf(a0.z,a0.w); w0[2]=pk2bf(a1.x,a1.y); w0[3]=pk2bf(a1.z,a1.w);
    w1[0]=pk2bf(a2.x,a2.y); w1[1]=pk2bf(a2.z,a2.w); w1[2]=pk2bf(a3.x,a3.y); w1[3]=pk2bf(a3.z,a3.w);
    *reinterpret_cast<u32x4*>(&As[0][awr])        = w0;
    *reinterpret_cast<u32x4*>(&As[0][4096 + awr]) = w1;
  } else {
    gload16(Ag0, &As[0][wb]);
    gload16(Ag1, &As[0][4096 + wb]);
    gload16(Bg0, &Bs[0][wb]);
    gload16(Bg1, &Bs[0][4096 + wb]);
  }
  __syncthreads();
  f32x4 acc[4][2] = {};
  int cur = 0;
  const int NS = 16;   // K/64 steps
#pragma unroll 1
  for (int ks = 0; ks < NS; ++ks){
    float4 a0, a1, a2, a3;
    if (ks + 1 < NS){
      const int kn = (ks + 1) * 64;
      if (AF32){
        a0 = *reinterpret_cast<const float4*>(Af0 + kn);
        a1 = *reinterpret_cast<const float4*>(Af0 + kn + 4);
        a2 = *reinterpret_cast<const float4*>(Af1 + kn);
        a3 = *reinterpret_cast<const float4*>(Af1 + kn + 4);
      } else {
        gload16(Ag0 + kn, &As[cur^1][wb]);
        gload16(Ag1 + kn, &As[cur^1][4096 + wb]);
      }
      gload16(Bg0 + kn, &Bs[cur^1][wb]);
      gload16(Bg1 + kn, &Bs[cur^1][4096 + wb]);
    }
    const u16* Ac = &As[cur][0];
    const u16* Bc = &Bs[cur][0];
    short8 af[2][4], bfr[2][2];
#pragma unroll
    for (int ks2=0;ks2<2;ks2++){
#pragma unroll
      for (int i=0;i<4;i++)
        af[ks2][i] = *reinterpret_cast<const short8*>(Ac + (wr + i*16 + l16)*64 + ((ks2*32 + lq*8) ^ rsw));
#pragma unroll
      for (int j=0;j<2;j++)
        bfr[ks2][j] = *reinterpret_cast<const short8*>(Bc + (wc + j*16 + l16)*64 + ((ks2*32 + lq*8) ^ rsw));
    }
    __builtin_amdgcn_s_setprio(1);
#pragma unroll
    for (int ks2=0;ks2<2;ks2++)
#pragma unroll
      for (int i=0;i<4;i++)
#pragma unroll
        for (int j=0;j<2;j++) acc[i][j] = mfma16(af[ks2][i], bfr[ks2][j], acc[i][j]);
    __builtin_amdgcn_s_setprio(0);
    if (AF32 && (ks + 1 < NS)){
      u32x4 w0, w1;
      w0[0]=pk2bf(a0.x,a0.y); w0[1]=pk2bf(a0.z,a0.w); w0[2]=pk2bf(a1.x,a1.y); w0[3]=pk2bf(a1.z,a1.w);
      w1[0]=pk2bf(a2.x,a2.y); w1[1]=pk2bf(a2.z,a2.w); w1[2]=pk2bf(a3.x,a3.y); w1[3]=pk2bf(a3.z,a3.w);
      *reinterpret_cast<u32x4*>(&As[cur^1][awr])        = w0;
      *reinterpret_cast<u32x4*>(&As[cur^1][4096 + awr]) = w1;
    }
    __syncthreads();   // prefetch (+A-write) landed; all waves done with cur
    cur ^= 1;
  }
#pragma unroll
  for (int i=0;i<4;i++){
#pragma unroll
    for (int j=0;j<2;j++){
      if (MODE == 4){
        // V^T: Vt[((b*H+h)*64+hd)*S + s], s = mb..mb+3 packed in one 8B store
        const int mb = m0 + wr + i*16 + lq*4;
        const int n  = n0 + wc + j*16 + l16;
        const int b = mb >> 11, s = mb & 2047;    // S_=2048
        const int h = n >> 6,  hd = n & 63;       // HD=64
        uint2 w;
        w.x = pk2bf(acc[i][j][0], acc[i][j][1]);
        w.y = pk2bf(acc[i][j][2], acc[i][j][3]);
        *reinterpret_cast<uint2*>(reinterpret_cast<u16*>(C) +
            ((size_t)((b*H_ + h)*64 + hd))*S_ + s) = w;
      } else {
#pragma unroll
        for (int r=0;r<4;r++){
          const int m = m0 + wr + i*16 + lq*4 + r;
          const int n = n0 + wc + j*16 + l16;
          reinterpret_cast<float*>(C)[(size_t)m * N + n] = acc[i][j][r];
        }
      }
    }
  }
}

// ---------------- causal flash attention (best measured config) -----------
// Q,K: [BH][S][64] (Q pre-scaled into exp2 domain), Vt: [BH][64][S], O: [B,S,D]
// One q-tile (128 rows, 4 waves x 32 q-cols) per block; grid (64,16) = 1024
// blocks = 4 blocks/CU; qt = 15-by -> heavy blocks first (LPT). bh fastest ->
// per-XCD L2 holds 8 heads' K/V. KV dbuf via gload_lds + XOR swizzle (32 KB).
// exp2-direct softmax; raw v_exp_f32 + v_cvt_pk_bf16_f32 pack; P -> PV
// B-frags via permlane32_swap; l via ones-MFMA. Measured 53.0 us stable.
__global__ __launch_bounds__(256, 4) void attn_kernel(const u16* __restrict__ Q,
                                                      const u16* __restrict__ Kg,
                                                      const u16* __restrict__ Vt,
                                                      u16* __restrict__ O){
  __shared__ __align__(16) u16 KV[2][2][4096];   // [buf][K|V][row*64+col] 32 KB
  const int bh = blockIdx.x;                     // fastest -> XCD = bh%8
  const int qt = 15 - blockIdx.y;                // heavy tiles first
  const int tid = threadIdx.x, wid = tid >> 6, lane = tid & 63;
  const int l32 = lane & 31, hh = lane >> 5;
  const u16* Qb = Q  + (size_t)bh * S_ * 64;
  const u16* Kb = Kg + (size_t)bh * S_ * 64;
  const u16* Vb = Vt + (size_t)bh * 64 * S_;
  const int b = bh >> 4, head = bh & 15;
  const short8 ones8 = {0x3F80,0x3F80,0x3F80,0x3F80,0x3F80,0x3F80,0x3F80,0x3F80};
  const f32x16 Z16 = {};

  // staging: thread covers 16B at rows (tid>>3) and (tid>>3)+32 of 64x64 tile
  const int LoffA = tid*8;                    // u16 offset, rows 0..31
  const int rowA  = tid >> 3;
  const int swzA  = LoffA ^ ((rowA & 7) << 3);
  const int swzB  = swzA + 2048;              // rows 32..63 (same row&7)
  const int vcolA = swzA & 63;                // col bits identical for both
  const int rsw   = (l32 & 7) << 3;           // read-side swizzle

  const int q0 = qt * 128;
  const int qw0 = q0 + wid*32;                // wave q base
  const int qg = qw0 + l32;                   // this lane's q row
  short8 qf[4];
#pragma unroll
  for (int j=0;j<4;j++)
    qf[j] = *reinterpret_cast<const short8*>(Qb + (size_t)qg*64 + j*16 + hh*8);
  f32x16 oacc0 = Z16, oacc1 = Z16, lacc = Z16;

  const int nt = 2*qt + 2;
  // prologue: stage tile 0 into buf 0 (K rows 0..63, V rows 0..63)
  gload16(Kb + swzA,                         &KV[0][0][wid*512]);
  gload16(Kb + swzB,                         &KV[0][0][wid*512 + 2048]);
  gload16(Vb + (size_t)rowA*S_ + vcolA,      &KV[0][1][wid*512]);
  gload16(Vb + (size_t)(rowA+32)*S_ + vcolA, &KV[0][1][wid*512 + 2048]);
  __syncthreads();

#pragma unroll 1
  for (int kt = 0; kt < nt; ++kt){
    const int cur = kt & 1;
    if (kt + 1 < nt){
      const int kn = (kt + 1) * 64;
      gload16(Kb + (size_t)kn*64 + swzA,             &KV[cur^1][0][wid*512]);
      gload16(Kb + (size_t)kn*64 + swzB,             &KV[cur^1][0][wid*512 + 2048]);
      gload16(Vb + (size_t)rowA*S_ + kn + vcolA,     &KV[cur^1][1][wid*512]);
      gload16(Vb + (size_t)(rowA+32)*S_ + kn + vcolA,&KV[cur^1][1][wid*512 + 2048]);
    }
    const int k0 = kt * 64;
    if (k0 <= qw0 + 31){   // wave has at least one unmasked q
      const u16* Kc = &KV[cur][0][0];
      const u16* Vc = &KV[cur][1][0];
      // QK^T: lane: q=l32, k = k0 + (r&3)+8(r>>2)+4hh (+32 for sc1)
      f32x16 sc0 = Z16, sc1 = Z16;
      __builtin_amdgcn_s_setprio(1);
#pragma unroll
      for (int j=0;j<4;j++){
        short8 kf0 = *reinterpret_cast<const short8*>(Kc + l32*64      + ((j*16 + hh*8) ^ rsw));
        short8 kf1 = *reinterpret_cast<const short8*>(Kc + (32+l32)*64 + ((j*16 + hh*8) ^ rsw));
        sc0 = mfma32(kf0, qf[j], sc0);
        sc1 = mfma32(kf1, qf[j], sc1);
      }
      __builtin_amdgcn_s_setprio(0);
      if (k0 + 63 > qw0){   // element mask in diagonal region
#pragma unroll
        for (int r=0;r<16;r++){
          const int kk = k0 + (r&3) + 8*(r>>2) + 4*hh;
          if (kk > qg)      sc0[r] = -1e30f;
          if (kk + 32 > qg) sc1[r] = -1e30f;
        }
      }
      // P = exp2(S) directly; raw v_exp_f32 (masked -1e30 -> 0)
#pragma unroll
      for (int r=0;r<16;r++){
        sc0[r] = rexp2(sc0[r]);
        sc1[r] = rexp2(sc1[r]);
      }
      // per 16-k block: pack to bf16, permlane-swap into PV B-frags, MFMA
      __builtin_amdgcn_s_setprio(1);
#pragma unroll
      for (int blk=0; blk<4; ++blk){
        const f32x16 S = (blk < 2) ? sc0 : sc1;
        const int r0 = (blk & 1) * 8;
        u32 a0 = cvtpk(S[r0+0], S[r0+1]);
        u32 a1 = cvtpk(S[r0+2], S[r0+3]);
        u32 b0 = cvtpk(S[r0+4], S[r0+5]);
        u32 b1 = cvtpk(S[r0+6], S[r0+7]);
        plswap(a0, b0);
        plswap(a1, b1);
        u32x4 t4; t4[0]=a0; t4[1]=a1; t4[2]=b0; t4[3]=b1;
        const short8 pf = __builtin_bit_cast(short8, t4);
        lacc = mfma32(ones8, pf, lacc);          // row-sum of P
        short8 vf0 = *reinterpret_cast<const short8*>(Vc + l32*64      + ((blk*16 + hh*8) ^ rsw));
        short8 vf1 = *reinterpret_cast<const short8*>(Vc + (32+l32)*64 + ((blk*16 + hh*8) ^ rsw));
        oacc0 = mfma32(vf0, pf, oacc0);
        oacc1 = mfma32(vf1, pf, oacc1);
      }
      __builtin_amdgcn_s_setprio(0);
    }
    __syncthreads();   // drains vmcnt (prefetch landed) + all waves done with cur
  }
  // epilogue: lacc[0] = sum_k P for q=qg; O[q][d], d = 32*dt + 8*q4 + 4*hh + j
  const float linv = __builtin_amdgcn_rcpf(lacc[0]);
  u16* Orow = O + (size_t)(b*S_ + qg)*D_ + head*64;
#pragma unroll
  for (int q4=0;q4<4;q4++){
    uint2 o0, o1;
    o0.x = pk2bf(oacc0[q4*4+0]*linv, oacc0[q4*4+1]*linv);
    o0.y = pk2bf(oacc0[q4*4+2]*linv, oacc0[q4*4+3]*linv);
    o1.x = pk2bf(oacc1[q4*4+0]*linv, oacc1[q4*4+1]*linv);
    o1.y = pk2bf(oacc1[q4*4+2]*linv, oacc1[q4*4+3]*linv);
    *reinterpret_cast<uint2*>(Orow + q4*8 + hh*4)      = o0;
    *reinterpret_cast<uint2*>(Orow + 32 + q4*8 + hh*4) = o1;
  }
}

extern "C" void kernel_launch(void* const* d_in, const int* in_sizes, int n_in,
                              void* d_out, int out_size, void* d_ws, size_t ws_size,
                              hipStream_t stream){
  const float* x  = (const float*)d_in[0];
  const float* Wq = (const float*)d_in[1];
  const float* Wk = (const float*)d_in[2];
  const float* Wv = (const float*)d_in[3];
  const float* Wo = (const float*)d_in[4];
  char* ws = (char*)d_ws;
  u16* Wqb = (u16*)(ws + (16u<<20));                   // 2 MiB
  u16* Wkb = (u16*)(ws + (16u<<20) + (2u<<20));
  u16* Wvb = (u16*)(ws + (16u<<20) + (4u<<20));
  u16* Wob = (u16*)(ws + (16u<<20) + (6u<<20));
  u16* Qh  = (u16*)(ws + (24u<<20));                   // 16 MiB [BH][S][64]
  u16* Kh  = (u16*)(ws + (40u<<20));                   // 16 MiB
  u16* Ob  = (u16*)(ws + (56u<<20));                   // 16 MiB attn out [B,S,D]
  u16* Vt  = (u16*)(ws + (72u<<20));                   // 16 MiB [BH][64][S]
  float2* tab = (float2*)(ws + (88u<<20));             // 512 KiB rope table

  prep_kernel<<<4352, 256, 0, stream>>>(Wq, Wk, Wv, Wo, Wqb, Wkb, Wvb, Wob, tab);

  dim3 gg(64, 8);
  gemm_qk<<<gg, 512, 0, stream>>>(x, Wqb, Wkb, Qh, Kh, tab);
  gemm_bt<4, true><<<gg, 512, 0, stream>>>(nullptr, x, Wvb, Vt, 8192, 1024, 1024);

  attn_kernel<<<dim3(64,16), 256, 0, stream>>>(Qh, Kh, Vt, Ob);

  gemm_bt<2, false><<<gg, 512, 0, stream>>>(Ob, nullptr, Wob, (float*)d_out, 8192, 1024, 1024);
}

// Round 26
// 155.742 us; speedup vs baseline: 1.3490x; 1.3490x over previous
//
#include <hip/hip_runtime.h>
#include <hip/hip_bf16.h>
#include <stdint.h>

#define B_ 4
#define S_ 2048
#define D_ 1024
#define H_ 16

typedef __attribute__((ext_vector_type(4))) float f32x4;
typedef __attribute__((ext_vector_type(16))) float f32x16;
typedef __attribute__((ext_vector_type(8))) short short8;
typedef __attribute__((ext_vector_type(8))) unsigned short ushort8;
typedef __attribute__((ext_vector_type(4))) unsigned int u32x4;
typedef unsigned short u16;
typedef unsigned int u32;

__device__ __forceinline__ u16 f2bf(float f){
  return __builtin_bit_cast(u16, __hip_bfloat16(f));
}
__device__ __forceinline__ u32 pk2bf(float a, float b){
  return (u32)f2bf(a) | ((u32)f2bf(b) << 16);
}
// raw v_exp_f32: skips the non-fast-math denormal guard sequence
__device__ __forceinline__ float rexp2(float x){
  float r; asm("v_exp_f32 %0, %1" : "=v"(r) : "v"(x)); return r;
}
// HW packed f32->bf16 pair convert: dst.lo=bf16(a), dst.hi=bf16(b)
__device__ __forceinline__ u32 cvtpk(float a, float b){
  u32 r; asm("v_cvt_pk_bf16_f32 %0, %1, %2" : "=v"(r) : "v"(a), "v"(b)); return r;
}
__device__ __forceinline__ f32x4 mfma16(short8 a, short8 b, f32x4 c){
  return __builtin_amdgcn_mfma_f32_16x16x32_bf16(a, b, c, 0, 0, 0);
}
__device__ __forceinline__ f32x16 mfma32(short8 a, short8 b, f32x16 c){
  return __builtin_amdgcn_mfma_f32_32x32x16_bf16(a, b, c, 0, 0, 0);
}
// swap upper half of x with lower half of y (v_permlane32_swap_b32)
__device__ __forceinline__ void plswap(u32 &x, u32 &y){
  asm volatile("v_permlane32_swap_b32 %0, %1" : "+v"(x), "+v"(y));
}
__device__ __forceinline__ void gload16(const u16* g, u16* l){
  __builtin_amdgcn_global_load_lds((const __attribute__((address_space(1))) u32*)g,
                                   (__attribute__((address_space(3))) u32*)l, 16, 0, 0);
}

// ---------------- merged prep: x cvt + 4 weight cvt + rope table ----------
__global__ __launch_bounds__(256) void prep_kernel(const float* __restrict__ x,
                                                   const float* __restrict__ w0, const float* __restrict__ w1,
                                                   const float* __restrict__ w2, const float* __restrict__ w3,
                                                   u16* __restrict__ xb,
                                                   u16* __restrict__ o0, u16* __restrict__ o1,
                                                   u16* __restrict__ o2, u16* __restrict__ o3,
                                                   float2* __restrict__ tab){
  const int gid = blockIdx.x;
  if (gid < 8192){
    const int i = gid * 256 + threadIdx.x;
    float4 v = reinterpret_cast<const float4*>(x)[i];
    uint2 o; o.x = pk2bf(v.x, v.y); o.y = pk2bf(v.z, v.w);
    reinterpret_cast<uint2*>(xb)[i] = o;
  } else if (gid < 12288){
    const int g = gid - 8192;
    const int which = g >> 10;
    const float* in = (which==0) ? w0 : (which==1) ? w1 : (which==2) ? w2 : w3;
    u16* out = (which==0) ? o0 : (which==1) ? o1 : (which==2) ? o2 : o3;
    const int i = (g & 1023) * 256 + threadIdx.x;
    float4 v = reinterpret_cast<const float4*>(in)[i];
    uint2 o; o.x = pk2bf(v.x, v.y); o.y = pk2bf(v.z, v.w);
    reinterpret_cast<uint2*>(out)[i] = o;
  } else {
    const int idx = (gid - 12288) * 256 + threadIdx.x;   // 65536
    const int i = idx & 31, s = idx >> 5;
    const float ang = (float)s * __builtin_exp2f((float)i * -0.41524101186092032f);
    float sn, cs;
    __sincosf(ang, &sn, &cs);
    tab[idx] = make_float2(cs, sn);
  }
}

// ---------------- merged Q+K projection GEMM ------------------------------
// Shares the A (=xb) staging between both weight matrices: A gloads and A
// HBM traffic halve; per 16 MFMA only 8 LDS frag reads (af reused).
// 8-wave 128x128 tile, BK=32 (3-matrix dbuf = 48 KB), 4-row XOR swizzle
// (BK=32 rows span 64B; (row&3)<<3 is the largest legal swizzle).
// Same proven dbuf + __syncthreads sync. Epilogue: RoPE for Q (x QS) and K.
__global__ __launch_bounds__(512) void gemm_qk(const u16* __restrict__ A,
                                               const u16* __restrict__ Wq,
                                               const u16* __restrict__ Wk,
                                               u16* __restrict__ Qh,
                                               u16* __restrict__ Kh,
                                               const float2* __restrict__ tab){
  __shared__ __align__(16) u16 As [2][128*32];   // 16 KB
  __shared__ __align__(16) u16 Bqs[2][128*32];   // 16 KB
  __shared__ __align__(16) u16 Bks[2][128*32];   // 16 KB
  const int K = 1024;
  const int tid = threadIdx.x;
  const int lane = tid & 63, wid = tid >> 6;      // 8 waves
  const int l16 = lane & 15, lq = lane >> 4;
  const int m0 = blockIdx.x * 128, n0 = blockIdx.y * 128;
  const int wr = (wid >> 2) * 64, wc = (wid & 3) * 32;
  // staging: thread t -> row t>>2 (0..127), col (t&3)*8 swizzled by row&3
  const int row_s = tid >> 2;
  const int csw = ((tid & 3) * 8) ^ ((row_s & 3) << 3);
  const u16* Ag = A  + (size_t)(m0 + row_s) * K + csw;
  const u16* Qg = Wq + (size_t)(n0 + row_s) * K + csw;
  const u16* Kg = Wk + (size_t)(n0 + row_s) * K + csw;
  const int wb = wid * 512;                       // wave staging base (u16)
  const int rsw = (l16 & 3) << 3;                 // read-side swizzle
  // prologue: stage k=0 into buf 0
  gload16(Ag, &As[0][wb]);
  gload16(Qg, &Bqs[0][wb]);
  gload16(Kg, &Bks[0][wb]);
  __syncthreads();
  f32x4 accQ[4][2] = {}, accK[4][2] = {};
  int cur = 0;
  const int NS = 32;   // K/32 steps
#pragma unroll 1
  for (int ks = 0; ks < NS; ++ks){
    if (ks + 1 < NS){
      const int kn = (ks + 1) * 32;
      gload16(Ag + kn, &As [cur^1][wb]);
      gload16(Qg + kn, &Bqs[cur^1][wb]);
      gload16(Kg + kn, &Bks[cur^1][wb]);
    }
    const u16* Ac  = &As [cur][0];
    const u16* Bqc = &Bqs[cur][0];
    const u16* Bkc = &Bks[cur][0];
    short8 af[4], bq[2], bk[2];
#pragma unroll
    for (int i=0;i<4;i++)
      af[i] = *reinterpret_cast<const short8*>(Ac + (wr + i*16 + l16)*32 + ((lq*8) ^ rsw));
#pragma unroll
    for (int j=0;j<2;j++){
      bq[j] = *reinterpret_cast<const short8*>(Bqc + (wc + j*16 + l16)*32 + ((lq*8) ^ rsw));
      bk[j] = *reinterpret_cast<const short8*>(Bkc + (wc + j*16 + l16)*32 + ((lq*8) ^ rsw));
    }
    __builtin_amdgcn_s_setprio(1);
#pragma unroll
    for (int i=0;i<4;i++)
#pragma unroll
      for (int j=0;j<2;j++){
        accQ[i][j] = mfma16(af[i], bq[j], accQ[i][j]);
        accK[i][j] = mfma16(af[i], bk[j], accK[i][j]);
      }
    __builtin_amdgcn_s_setprio(0);
    __syncthreads();   // prefetch landed + all waves done with buf[cur]
    cur ^= 1;
  }
  const float QS = 0.18033688011112043f;  // 0.125 * log2(e)
#pragma unroll
  for (int i=0;i<4;i++){
#pragma unroll
    for (int j=0;j<2;j++){
#pragma unroll
      for (int r=0;r<4;r++){
        const int m = m0 + wr + i*16 + lq*4 + r;
        const int n = n0 + wc + j*16 + l16;
        const int b = m >> 11, s = m & 2047;    // S_=2048
        const int h = n >> 6,  hd = n & 63;     // HD=64
        const float2 t = tab[(s << 5) + (hd >> 1)];
        const size_t dst = (((size_t)(b*H_ + h) * S_ + s) << 6) + hd;
        {
          float v = accQ[i][j][r];
          const float partner = __shfl_xor(v, 1, 64);
          const float pm = (hd & 1) ? partner : -partner;
          Qh[dst] = f2bf(fmaf(v, t.x, pm * t.y) * QS);
        }
        {
          float v = accK[i][j][r];
          const float partner = __shfl_xor(v, 1, 64);
          const float pm = (hd & 1) ? partner : -partner;
          Kh[dst] = f2bf(fmaf(v, t.x, pm * t.y));
        }
      }
    }
  }
}

// ---------------- GEMM: C[M,N] = A[M,K] * B[N,K]^T (bf16 in) -------------
// 8-wave 128x128 tile, BK=64, double-buffered via __syncthreads.
// T2 both-sides XOR swizzle; 16 MFMA/wave per barrier. Determinism-verified.
// MODE 2: f32 [M][N];  MODE 4: bf16 V^T -> [BH][HD=64][S].
template<int MODE>
__global__ __launch_bounds__(512) void gemm_bt(const u16* __restrict__ A,
                                               const u16* __restrict__ Bw,
                                               void* __restrict__ C,
                                               const float2* __restrict__ tab,
                                               int M, int N, int K){
  __shared__ __align__(16) u16 As[2][128*64];   // 32 KB
  __shared__ __align__(16) u16 Bs[2][128*64];   // 32 KB
  const int tid = threadIdx.x;
  const int lane = tid & 63, wid = tid >> 6;      // 8 waves
  const int l16 = lane & 15, lq = lane >> 4;
  const int m0 = blockIdx.x * 128, n0 = blockIdx.y * 128;
  const int wr = (wid >> 2) * 64, wc = (wid & 3) * 32;
  const int row_s = tid >> 3;                     // 0..63
  const int csw = ((tid & 7) * 8) ^ ((row_s & 7) << 3);
  const u16* Ag0 = A  + (size_t)(m0 + row_s     ) * K + csw;
  const u16* Ag1 = A  + (size_t)(m0 + 64 + row_s) * K + csw;
  const u16* Bg0 = Bw + (size_t)(n0 + row_s     ) * K + csw;
  const u16* Bg1 = Bw + (size_t)(n0 + 64 + row_s) * K + csw;
  const int wb = wid * 512;                       // wave staging base (u16)
  const int rsw = (l16 & 7) << 3;                 // read-side swizzle
  gload16(Ag0, &As[0][wb]);
  gload16(Ag1, &As[0][4096 + wb]);
  gload16(Bg0, &Bs[0][wb]);
  gload16(Bg1, &Bs[0][4096 + wb]);
  __syncthreads();
  f32x4 acc[4][2] = {};
  int cur = 0;
  const int NS = 16;   // K/64 steps
#pragma unroll 1
  for (int ks = 0; ks < NS; ++ks){
    if (ks + 1 < NS){
      const int kn = (ks + 1) * 64;
      gload16(Ag0 + kn, &As[cur^1][wb]);
      gload16(Ag1 + kn, &As[cur^1][4096 + wb]);
      gload16(Bg0 + kn, &Bs[cur^1][wb]);
      gload16(Bg1 + kn, &Bs[cur^1][4096 + wb]);
    }
    const u16* Ac = &As[cur][0];
    const u16* Bc = &Bs[cur][0];
    short8 af[2][4], bfr[2][2];
#pragma unroll
    for (int ks2=0;ks2<2;ks2++){
#pragma unroll
      for (int i=0;i<4;i++)
        af[ks2][i] = *reinterpret_cast<const short8*>(Ac + (wr + i*16 + l16)*64 + ((ks2*32 + lq*8) ^ rsw));
#pragma unroll
      for (int j=0;j<2;j++)
        bfr[ks2][j] = *reinterpret_cast<const short8*>(Bc + (wc + j*16 + l16)*64 + ((ks2*32 + lq*8) ^ rsw));
    }
    __builtin_amdgcn_s_setprio(1);
#pragma unroll
    for (int ks2=0;ks2<2;ks2++)
#pragma unroll
      for (int i=0;i<4;i++)
#pragma unroll
        for (int j=0;j<2;j++) acc[i][j] = mfma16(af[ks2][i], bfr[ks2][j], acc[i][j]);
    __builtin_amdgcn_s_setprio(0);
    __syncthreads();   // prefetch landed + all waves done with buf[cur]
    cur ^= 1;
  }
#pragma unroll
  for (int i=0;i<4;i++){
#pragma unroll
    for (int j=0;j<2;j++){
      if (MODE == 4){
        // V^T: Vt[((b*H+h)*64+hd)*S + s], s = mb..mb+3 packed in one 8B store
        const int mb = m0 + wr + i*16 + lq*4;
        const int n  = n0 + wc + j*16 + l16;
        const int b = mb >> 11, s = mb & 2047;    // S_=2048
        const int h = n >> 6,  hd = n & 63;       // HD=64
        uint2 w;
        w.x = pk2bf(acc[i][j][0], acc[i][j][1]);
        w.y = pk2bf(acc[i][j][2], acc[i][j][3]);
        *reinterpret_cast<uint2*>(reinterpret_cast<u16*>(C) +
            ((size_t)((b*H_ + h)*64 + hd))*S_ + s) = w;
      } else {
#pragma unroll
        for (int r=0;r<4;r++){
          const int m = m0 + wr + i*16 + lq*4 + r;
          const int n = n0 + wc + j*16 + l16;
          reinterpret_cast<float*>(C)[(size_t)m * N + n] = acc[i][j][r];
        }
      }
    }
  }
}

// ---------------- causal flash attention (best measured config) -----------
// Q,K: [BH][S][64] (Q pre-scaled into exp2 domain), Vt: [BH][64][S], O: [B,S,D]
// One q-tile (128 rows, 4 waves x 32 q-cols) per block; grid (64,16) = 1024
// blocks = 4 blocks/CU; qt = 15-by -> heavy blocks first (LPT). bh fastest ->
// per-XCD L2 holds 8 heads' K/V. KV dbuf via gload_lds + XOR swizzle (32 KB).
// exp2-direct softmax; raw v_exp_f32 + v_cvt_pk_bf16_f32 pack; P -> PV
// B-frags via permlane32_swap; l via ones-MFMA. Measured 53.0 us stable.
__global__ __launch_bounds__(256, 4) void attn_kernel(const u16* __restrict__ Q,
                                                      const u16* __restrict__ Kg,
                                                      const u16* __restrict__ Vt,
                                                      u16* __restrict__ O){
  __shared__ __align__(16) u16 KV[2][2][4096];   // [buf][K|V][row*64+col] 32 KB
  const int bh = blockIdx.x;                     // fastest -> XCD = bh%8
  const int qt = 15 - blockIdx.y;                // heavy tiles first
  const int tid = threadIdx.x, wid = tid >> 6, lane = tid & 63;
  const int l32 = lane & 31, hh = lane >> 5;
  const u16* Qb = Q  + (size_t)bh * S_ * 64;
  const u16* Kb = Kg + (size_t)bh * S_ * 64;
  const u16* Vb = Vt + (size_t)bh * 64 * S_;
  const int b = bh >> 4, head = bh & 15;
  const short8 ones8 = {0x3F80,0x3F80,0x3F80,0x3F80,0x3F80,0x3F80,0x3F80,0x3F80};
  const f32x16 Z16 = {};

  // staging: thread covers 16B at rows (tid>>3) and (tid>>3)+32 of 64x64 tile
  const int LoffA = tid*8;                    // u16 offset, rows 0..31
  const int rowA  = tid >> 3;
  const int swzA  = LoffA ^ ((rowA & 7) << 3);
  const int swzB  = swzA + 2048;              // rows 32..63 (same row&7)
  const int vcolA = swzA & 63;                // col bits identical for both
  const int rsw   = (l32 & 7) << 3;           // read-side swizzle

  const int q0 = qt * 128;
  const int qw0 = q0 + wid*32;                // wave q base
  const int qg = qw0 + l32;                   // this lane's q row
  short8 qf[4];
#pragma unroll
  for (int j=0;j<4;j++)
    qf[j] = *reinterpret_cast<const short8*>(Qb + (size_t)qg*64 + j*16 + hh*8);
  f32x16 oacc0 = Z16, oacc1 = Z16, lacc = Z16;

  const int nt = 2*qt + 2;
  // prologue: stage tile 0 into buf 0 (K rows 0..63, V rows 0..63)
  gload16(Kb + swzA,                         &KV[0][0][wid*512]);
  gload16(Kb + swzB,                         &KV[0][0][wid*512 + 2048]);
  gload16(Vb + (size_t)rowA*S_ + vcolA,      &KV[0][1][wid*512]);
  gload16(Vb + (size_t)(rowA+32)*S_ + vcolA, &KV[0][1][wid*512 + 2048]);
  __syncthreads();

#pragma unroll 1
  for (int kt = 0; kt < nt; ++kt){
    const int cur = kt & 1;
    if (kt + 1 < nt){
      const int kn = (kt + 1) * 64;
      gload16(Kb + (size_t)kn*64 + swzA,             &KV[cur^1][0][wid*512]);
      gload16(Kb + (size_t)kn*64 + swzB,             &KV[cur^1][0][wid*512 + 2048]);
      gload16(Vb + (size_t)rowA*S_ + kn + vcolA,     &KV[cur^1][1][wid*512]);
      gload16(Vb + (size_t)(rowA+32)*S_ + kn + vcolA,&KV[cur^1][1][wid*512 + 2048]);
    }
    const int k0 = kt * 64;
    if (k0 <= qw0 + 31){   // wave has at least one unmasked q
      const u16* Kc = &KV[cur][0][0];
      const u16* Vc = &KV[cur][1][0];
      // QK^T: lane: q=l32, k = k0 + (r&3)+8(r>>2)+4hh (+32 for sc1)
      f32x16 sc0 = Z16, sc1 = Z16;
      __builtin_amdgcn_s_setprio(1);
#pragma unroll
      for (int j=0;j<4;j++){
        short8 kf0 = *reinterpret_cast<const short8*>(Kc + l32*64      + ((j*16 + hh*8) ^ rsw));
        short8 kf1 = *reinterpret_cast<const short8*>(Kc + (32+l32)*64 + ((j*16 + hh*8) ^ rsw));
        sc0 = mfma32(kf0, qf[j], sc0);
        sc1 = mfma32(kf1, qf[j], sc1);
      }
      __builtin_amdgcn_s_setprio(0);
      if (k0 + 63 > qw0){   // element mask in diagonal region
#pragma unroll
        for (int r=0;r<16;r++){
          const int kk = k0 + (r&3) + 8*(r>>2) + 4*hh;
          if (kk > qg)      sc0[r] = -1e30f;
          if (kk + 32 > qg) sc1[r] = -1e30f;
        }
      }
      // P = exp2(S) directly; raw v_exp_f32 (masked -1e30 -> 0)
#pragma unroll
      for (int r=0;r<16;r++){
        sc0[r] = rexp2(sc0[r]);
        sc1[r] = rexp2(sc1[r]);
      }
      // per 16-k block: pack to bf16, permlane-swap into PV B-frags, MFMA
      __builtin_amdgcn_s_setprio(1);
#pragma unroll
      for (int blk=0; blk<4; ++blk){
        const f32x16 S = (blk < 2) ? sc0 : sc1;
        const int r0 = (blk & 1) * 8;
        u32 a0 = cvtpk(S[r0+0], S[r0+1]);
        u32 a1 = cvtpk(S[r0+2], S[r0+3]);
        u32 b0 = cvtpk(S[r0+4], S[r0+5]);
        u32 b1 = cvtpk(S[r0+6], S[r0+7]);
        plswap(a0, b0);
        plswap(a1, b1);
        u32x4 t4; t4[0]=a0; t4[1]=a1; t4[2]=b0; t4[3]=b1;
        const short8 pf = __builtin_bit_cast(short8, t4);
        lacc = mfma32(ones8, pf, lacc);          // row-sum of P
        short8 vf0 = *reinterpret_cast<const short8*>(Vc + l32*64      + ((blk*16 + hh*8) ^ rsw));
        short8 vf1 = *reinterpret_cast<const short8*>(Vc + (32+l32)*64 + ((blk*16 + hh*8) ^ rsw));
        oacc0 = mfma32(vf0, pf, oacc0);
        oacc1 = mfma32(vf1, pf, oacc1);
      }
      __builtin_amdgcn_s_setprio(0);
    }
    __syncthreads();   // drains vmcnt (prefetch landed) + all waves done with cur
  }
  // epilogue: lacc[0] = sum_k P for q=qg; O[q][d], d = 32*dt + 8*q4 + 4*hh + j
  const float linv = __builtin_amdgcn_rcpf(lacc[0]);
  u16* Orow = O + (size_t)(b*S_ + qg)*D_ + head*64;
#pragma unroll
  for (int q4=0;q4<4;q4++){
    uint2 o0, o1;
    o0.x = pk2bf(oacc0[q4*4+0]*linv, oacc0[q4*4+1]*linv);
    o0.y = pk2bf(oacc0[q4*4+2]*linv, oacc0[q4*4+3]*linv);
    o1.x = pk2bf(oacc1[q4*4+0]*linv, oacc1[q4*4+1]*linv);
    o1.y = pk2bf(oacc1[q4*4+2]*linv, oacc1[q4*4+3]*linv);
    *reinterpret_cast<uint2*>(Orow + q4*8 + hh*4)      = o0;
    *reinterpret_cast<uint2*>(Orow + 32 + q4*8 + hh*4) = o1;
  }
}

extern "C" void kernel_launch(void* const* d_in, const int* in_sizes, int n_in,
                              void* d_out, int out_size, void* d_ws, size_t ws_size,
                              hipStream_t stream){
  const float* x  = (const float*)d_in[0];
  const float* Wq = (const float*)d_in[1];
  const float* Wk = (const float*)d_in[2];
  const float* Wv = (const float*)d_in[3];
  const float* Wo = (const float*)d_in[4];
  char* ws = (char*)d_ws;
  u16* xb  = (u16*)(ws);                               // 16 MiB  x bf16
  u16* Wqb = (u16*)(ws + (16u<<20));                   // 2 MiB
  u16* Wkb = (u16*)(ws + (16u<<20) + (2u<<20));
  u16* Wvb = (u16*)(ws + (16u<<20) + (4u<<20));
  u16* Wob = (u16*)(ws + (16u<<20) + (6u<<20));
  u16* Qh  = (u16*)(ws + (24u<<20));                   // 16 MiB [BH][S][64]
  u16* Kh  = (u16*)(ws + (40u<<20));                   // 16 MiB
  u16* Ob  = (u16*)(ws + (56u<<20));                   // 16 MiB attn out [B,S,D]
  u16* Vt  = (u16*)(ws + (72u<<20));                   // 16 MiB [BH][64][S]
  float2* tab = (float2*)(ws + (88u<<20));             // 512 KiB rope table

  prep_kernel<<<12544, 256, 0, stream>>>(x, Wq, Wk, Wv, Wo, xb, Wqb, Wkb, Wvb, Wob, tab);

  dim3 gg(64, 8);
  gemm_qk<<<gg, 512, 0, stream>>>(xb, Wqb, Wkb, Qh, Kh, tab);
  gemm_bt<4><<<gg, 512, 0, stream>>>(xb, Wvb, Vt, nullptr, 8192, 1024, 1024);

  attn_kernel<<<dim3(64,16), 256, 0, stream>>>(Qh, Kh, Vt, Ob);

  gemm_bt<2><<<gg, 512, 0, stream>>>(Ob, Wob, (float*)d_out, nullptr, 8192, 1024, 1024);
}